// Round 1
// 2340.838 us; speedup vs baseline: 1.1210x; 1.1210x over previous
//
#include <hip/hip_runtime.h>
#include <hip/hip_bf16.h>
#include <math.h>

#define S 2048
#define H 4096
#define NH 32
#define HD 128
#define INTER 11008

typedef unsigned short u16;
typedef __attribute__((ext_vector_type(8))) short bf16x8;
typedef __attribute__((ext_vector_type(4))) float f32x4;

// round-to-nearest-even f32 -> bf16 (exact for ints |x| <= 256)
__device__ __forceinline__ u16 f2b(float f) {
    unsigned u = __float_as_uint(f);
    unsigned r = (u + 0x7fffu + ((u >> 16) & 1u)) >> 16;
    return (u16)r;
}
__device__ __forceinline__ float b2f(u16 u) {
    return __uint_as_float(((unsigned)u) << 16);
}
// split f32 into hi+lo bf16 (x ~= hi+lo to 2^-18 rel)
__device__ __forceinline__ void split2(float v, u16* hi, u16* lo) {
    u16 h = f2b(v);
    *hi = h;
    *lo = f2b(v - b2f(h));
}

__device__ __forceinline__ void gl_lds16(const void* g, void* l) {
    __builtin_amdgcn_global_load_lds((const __attribute__((address_space(1))) void*)g,
                                     (__attribute__((address_space(3))) void*)l, 16, 0, 0);
}

// granule swizzle for 128B-stride LDS tiles: spreads BOTH row-low-bit readers
// (c axis) and row-high-bit writers (dg axis) across the 8 16B-granules/row.
__device__ __forceinline__ int swz8(int r) { return (r ^ (r >> 3)) & 7; }

// ---------------- rmsnorm + CSM gather + quant -> bf16 int values ----------
__global__ __launch_bounds__(256)
void rmsnorm_csm_quant(const float* __restrict__ x, const float* __restrict__ w,
                       u16* __restrict__ out) {
    const int s = blockIdx.x, tid = threadIdx.x;
    const float* xr = x + (size_t)s * H;
    float ss = 0.f;
#pragma unroll
    for (int i = 0; i < 16; ++i) { float v = xr[tid + i * 256]; ss += v * v; }
#pragma unroll
    for (int off = 32; off >= 1; off >>= 1) ss += __shfl_xor(ss, off, 64);
    __shared__ float red[4];
    if ((tid & 63) == 0) red[tid >> 6] = ss;
    __syncthreads();
    float tot = red[0] + red[1] + red[2] + red[3];
    float scale = 1.0f / sqrtf(tot * (1.0f / H) + 1e-6f);
    u16* orow = out + (size_t)s * H;
#pragma unroll
    for (int i = 0; i < 16; ++i) {
        int j = tid + i * 256;
        int src = (j <= 19) ? 0 : ((j <= 38) ? (2 * j - 38) : j);
        float v = xr[src] * scale * w[src];
        float qv = fminf(fmaxf(rintf(v), -128.f), 127.f);
        orow[j] = f2b(qv);
    }
}

// ---------------- f32 -> bf16 weight convert (values are small ints) -------
__global__ __launch_bounds__(256)
void cvt_f32_bf16(const float4* __restrict__ src, ushort4* __restrict__ dst, int n4) {
    for (int i = blockIdx.x * 256 + threadIdx.x; i < n4; i += gridDim.x * 256) {
        float4 v = src[i];
        ushort4 o;
        o.x = f2b(v.x); o.y = f2b(v.y); o.z = f2b(v.z); o.w = f2b(v.w);
        dst[i] = o;
    }
}

// ---------------- quantize f32 ctx -> int bf16 -----------------------------
__global__ __launch_bounds__(256)
void quant_to_bf16(const float4* __restrict__ src, ushort4* __restrict__ dst, int n4) {
    for (int i = blockIdx.x * 256 + threadIdx.x; i < n4; i += gridDim.x * 256) {
        float4 v = src[i];
        ushort4 o;
        o.x = f2b(fminf(fmaxf(rintf(v.x), -128.f), 127.f));
        o.y = f2b(fminf(fmaxf(rintf(v.y), -128.f), 127.f));
        o.z = f2b(fminf(fmaxf(rintf(v.z), -128.f), 127.f));
        o.w = f2b(fminf(fmaxf(rintf(v.w), -128.f), 127.f));
        dst[i] = o;
    }
}

// ---------------- rope table (f64 trig, 2048 x 64 pairs) -------------------
__global__ void rope_table(const int* __restrict__ pos, float* __restrict__ tab) {
    int s = blockIdx.x, i = threadIdx.x;  // block = 64 threads
    double inv = pow(10000.0, -(double)(2 * i) / 128.0);
    double ang = (double)pos[s] * inv;
    tab[s * 128 + 2 * i]     = (float)cos(ang);
    tab[s * 128 + 2 * i + 1] = (float)sin(ang);
}

// ---------------- apply rope, emit hi/lo split bf16 q/k --------------------
__global__ __launch_bounds__(256)
void rope_apply(const float* __restrict__ q32, const float* __restrict__ k32,
                const float* __restrict__ tab,
                u16* __restrict__ qh, u16* __restrict__ ql,
                u16* __restrict__ kh, u16* __restrict__ kl) {
    int idx = blockIdx.x * 256 + threadIdx.x;   // S*NH*64
    int s = idx >> 11;
    int hh = (idx >> 6) & 31;
    int i = idx & 63;
    size_t base = (size_t)s * H + hh * HD + i;
    float cs = tab[s * 128 + 2 * i], sn = tab[s * 128 + 2 * i + 1];
    float a = q32[base], b = q32[base + 64];
    split2(a * cs - b * sn, &qh[base], &ql[base]);
    split2(b * cs + a * sn, &qh[base + 64], &ql[base + 64]);
    float c = k32[base], d = k32[base + 64];
    split2(c * cs - d * sn, &kh[base], &kl[base]);
    split2(d * cs + c * sn, &kh[base + 64], &kl[base + 64]);
}

// ---------------- GEMM: C[m,n] = alpha * sum_k A[m,k]*B[n,k] + bias[n] -----
// A: [2048][K] bf16, B: [N][K] bf16 (both K-contiguous). 128x128 tile, BK=64.
// EPI: 0 = store f32; 1 = store hi/lo split bf16 (outb,outb2); 2 = f32 +
//      extra (residual); 3 = gate (silu(val) * extra, quantize, store bf16)
template <int EPI>
__global__ __launch_bounds__(256)
void gemm_bt(const u16* __restrict__ A, const u16* __restrict__ B,
             const float* __restrict__ bias, float alpha, int N, int K,
             float* __restrict__ outf, u16* __restrict__ outb,
             u16* __restrict__ outb2, const float* __restrict__ extra) {
    __shared__ u16 As[128 * 64];
    __shared__ u16 Bs[128 * 64];
    const int tid = threadIdx.x;
    const int wave = tid >> 6, lane = tid & 63;
    const int mb = blockIdx.x, nb = blockIdx.y;
    const int waveM = wave & 1, waveN = wave >> 1;
    const int m0 = mb * 128, n0 = nb * 128;
    const int lrow = lane >> 3, lk8 = (lane & 7) * 8;
    const int q = lane >> 4, c = lane & 15;
    f32x4 acc[4][4] = {};
    for (int k0 = 0; k0 < K; k0 += 64) {
#pragma unroll
        for (int i = 0; i < 4; ++i) {
            int ch = wave * 4 + i;
            const u16* ga = A + (size_t)(m0 + ch * 8 + lrow) * K + k0 + lk8;
            gl_lds16(ga, (void*)((char*)As + ch * 1024));
            const u16* gb = B + (size_t)(n0 + ch * 8 + lrow) * K + k0 + lk8;
            gl_lds16(gb, (void*)((char*)Bs + ch * 1024));
        }
        __syncthreads();
#pragma unroll
        for (int kk = 0; kk < 2; ++kk) {
            bf16x8 af[4], bff[4];
#pragma unroll
            for (int t = 0; t < 4; ++t)
                af[t] = *(const bf16x8*)&As[(waveM * 64 + t * 16 + c) * 64 + kk * 32 + q * 8];
#pragma unroll
            for (int t = 0; t < 4; ++t)
                bff[t] = *(const bf16x8*)&Bs[(waveN * 64 + t * 16 + c) * 64 + kk * 32 + q * 8];
#pragma unroll
            for (int im = 0; im < 4; ++im)
#pragma unroll
                for (int in = 0; in < 4; ++in)
                    acc[im][in] = __builtin_amdgcn_mfma_f32_16x16x32_bf16(
                        af[im], bff[in], acc[im][in], 0, 0, 0);
        }
        __syncthreads();
    }
#pragma unroll
    for (int im = 0; im < 4; ++im) {
#pragma unroll
        for (int in = 0; in < 4; ++in) {
#pragma unroll
            for (int r = 0; r < 4; ++r) {
                int row = m0 + waveM * 64 + im * 16 + q * 4 + r;
                int col = n0 + waveN * 64 + in * 16 + c;
                float val = acc[im][in][r] * alpha + bias[col];
                size_t o = (size_t)row * N + col;
                if (EPI == 0) {
                    outf[o] = val;
                } else if (EPI == 1) {
                    split2(val, &outb[o], &outb2[o]);
                } else if (EPI == 2) {
                    outf[o] = val + extra[o];
                } else {
                    float x1 = val / (1.f + __expf(-val));
                    float p = x1 * extra[o];
                    float qv = fminf(fmaxf(rintf(p), -128.f), 127.f);
                    outb[o] = f2b(qv);
                }
            }
        }
    }
}

// ---------------- flash attention, split-bf16 (emulated fp32) MFMA ---------
// grid (NH, S/64); block 256 = 4 waves; wave w owns q rows qb*64+w*16 .. +15
// All LDS tiles are granule-XOR-swizzled (bank-conflict fix):
//  K  [64][128]: 16-granule space, f(row)=row&15; gl_lds16 writes linearly so
//                the swizzle is applied on the per-lane GLOBAL source granule
//                (rule: both-sides-or-neither, same involution).
//  V/P [*][64]:  8-granule space, f(row)=(row^(row>>3))&7 — low row bits fix
//                the strided reads, the folded-in row>>3 fixes the transpose
//                scatter-writes (rows vary by dg there).
__global__ __launch_bounds__(256)
void attn(const u16* __restrict__ Qh, const u16* __restrict__ Ql,
          const u16* __restrict__ Kh, const u16* __restrict__ Kl,
          const u16* __restrict__ Vh, const u16* __restrict__ Vl,
          float* __restrict__ ctx) {
    __shared__ u16 Ksh[64 * 128];   // [key][d]   (granule-swizzled)
    __shared__ u16 Ksl[64 * 128];
    __shared__ u16 Vth[128 * 64];   // [d][key]   (granule-swizzled)
    __shared__ u16 Vtl[128 * 64];
    __shared__ u16 Psh[4][16 * 64]; // per-wave P, A-layout [m][key] (swizzled)
    __shared__ u16 Psl[4][16 * 64];
    const int hh = blockIdx.x, qb = blockIdx.y;
    const int tid = threadIdx.x, wave = tid >> 6, lane = tid & 63;
    const int quad = lane >> 4, c = lane & 15;
    const int q0w = qb * 64 + wave * 16;
    const int swzc = swz8(c);       // f(row) for rows 0..15 read along c

    bf16x8 qfh[4], qfl[4];
#pragma unroll
    for (int ks = 0; ks < 4; ++ks) {
        size_t o = (size_t)(q0w + c) * H + hh * HD + ks * 32 + quad * 8;
        qfh[ks] = *(const bf16x8*)(Qh + o);
        qfl[ks] = *(const bf16x8*)(Ql + o);
    }

    f32x4 oacc[8] = {};
    float mi[4], li[4];
#pragma unroll
    for (int r = 0; r < 4; ++r) { mi[r] = -1e30f; li[r] = 0.f; }

    const int ntiles = qb + 1;
    for (int kt = 0; kt < ntiles; ++kt) {
        const int k0 = kt * 64;
        // stage K hi/lo tiles via global_load_lds (row-major [64][128]).
        // LDS dest is linear; source granule pre-swizzled by c ^ (row&15).
#pragma unroll
        for (int i2 = 0; i2 < 4; ++i2) {
            int ch = wave * 4 + i2;
            int krow = ch * 4 + quad;
            int cs = c ^ (krow & 15);
            size_t go = (size_t)(k0 + krow) * H + hh * HD + cs * 8;
            gl_lds16(Kh + go, (void*)((char*)Ksh + ch * 1024));
            gl_lds16(Kl + go, (void*)((char*)Ksl + ch * 1024));
        }
        // stage V hi/lo transposed: Vt[d][key], key-granule swizzled by swz8(d)
#pragma unroll
        for (int i2 = 0; i2 < 4; ++i2) {
            int cc = i2 * 256 + tid;
            int key = cc >> 4, dg = cc & 15;
            size_t go = (size_t)(k0 + key) * H + hh * HD + dg * 8;
            uint4 hv = *(const uint4*)(Vh + go);
            uint4 lv = *(const uint4*)(Vl + go);
            u16 eh[8], el[8];
            *(uint4*)eh = hv;
            *(uint4*)el = lv;
#pragma unroll
            for (int j = 0; j < 8; ++j) {
                int vrow = dg * 8 + j;
                int col = key ^ (swz8(vrow) << 3);   // swz8 = (j^dg)&7 here
                Vth[vrow * 64 + col] = eh[j];
                Vtl[vrow * 64 + col] = el[j];
            }
        }
        __syncthreads();
        // scores: sc = qh*kh + qh*kl + ql*kh   (emulated fp32)
        f32x4 sc[4] = {};
#pragma unroll
        for (int ks = 0; ks < 4; ++ks) {
#pragma unroll
            for (int nt = 0; nt < 4; ++nt) {
                int ko = (nt * 16 + c) * 128 + (((ks * 4 + quad) ^ c) * 8);
                bf16x8 kfh = *(const bf16x8*)&Ksh[ko];
                bf16x8 kfl = *(const bf16x8*)&Ksl[ko];
                sc[nt] = __builtin_amdgcn_mfma_f32_16x16x32_bf16(qfh[ks], kfh, sc[nt], 0, 0, 0);
                sc[nt] = __builtin_amdgcn_mfma_f32_16x16x32_bf16(qfh[ks], kfl, sc[nt], 0, 0, 0);
                sc[nt] = __builtin_amdgcn_mfma_f32_16x16x32_bf16(qfl[ks], kfh, sc[nt], 0, 0, 0);
            }
        }
        // scale + causal mask
#pragma unroll
        for (int nt = 0; nt < 4; ++nt)
#pragma unroll
            for (int r = 0; r < 4; ++r) {
                float v = sc[nt][r] * 0.08838834764831845f;
                int key = k0 + nt * 16 + c, qrow = q0w + quad * 4 + r;
                sc[nt][r] = (key > qrow) ? -1e30f : v;
            }
        // online softmax
#pragma unroll
        for (int r = 0; r < 4; ++r) {
            float mx = fmaxf(fmaxf(sc[0][r], sc[1][r]), fmaxf(sc[2][r], sc[3][r]));
#pragma unroll
            for (int off = 8; off >= 1; off >>= 1) mx = fmaxf(mx, __shfl_xor(mx, off, 64));
            float mnew = fmaxf(mi[r], mx);
            float al = __expf(mi[r] - mnew);
            float rs = 0.f;
#pragma unroll
            for (int nt = 0; nt < 4; ++nt) {
                float p = __expf(sc[nt][r] - mnew);
                sc[nt][r] = p;
                rs += p;
            }
#pragma unroll
            for (int off = 8; off >= 1; off >>= 1) rs += __shfl_xor(rs, off, 64);
            li[r] = li[r] * al + rs;
            mi[r] = mnew;
#pragma unroll
            for (int dt = 0; dt < 8; ++dt) oacc[dt][r] *= al;
        }
        // P -> LDS hi/lo (A-operand layout, granule-swizzled)
#pragma unroll
        for (int nt = 0; nt < 4; ++nt)
#pragma unroll
            for (int r = 0; r < 4; ++r) {
                int prow = quad * 4 + r;
                int o = prow * 64 + ((nt * 16 + c) ^ (swz8(prow) << 3));
                split2(sc[nt][r], &Psh[wave][o], &Psl[wave][o]);
            }
        __syncthreads();
        // PV: oacc += ph*vh + ph*vl + pl*vh
#pragma unroll
        for (int ks2 = 0; ks2 < 2; ++ks2) {
            int po = c * 64 + (((ks2 * 4 + quad) ^ swzc) * 8);
            bf16x8 pfh = *(const bf16x8*)&Psh[wave][po];
            bf16x8 pfl = *(const bf16x8*)&Psl[wave][po];
#pragma unroll
            for (int dt = 0; dt < 8; ++dt) {
                int vrow = dt * 16 + c;
                int vo = vrow * 64 + (((ks2 * 4 + quad) ^ swz8(vrow)) * 8);
                bf16x8 vfh = *(const bf16x8*)&Vth[vo];
                bf16x8 vfl = *(const bf16x8*)&Vtl[vo];
                oacc[dt] = __builtin_amdgcn_mfma_f32_16x16x32_bf16(pfh, vfh, oacc[dt], 0, 0, 0);
                oacc[dt] = __builtin_amdgcn_mfma_f32_16x16x32_bf16(pfh, vfl, oacc[dt], 0, 0, 0);
                oacc[dt] = __builtin_amdgcn_mfma_f32_16x16x32_bf16(pfl, vfh, oacc[dt], 0, 0, 0);
            }
        }
        __syncthreads();
    }
#pragma unroll
    for (int dt = 0; dt < 8; ++dt)
#pragma unroll
        for (int r = 0; r < 4; ++r)
            ctx[(size_t)(q0w + quad * 4 + r) * H + hh * HD + dt * 16 + c] =
                oacc[dt][r] / li[r];
}

// ---------------- host ------------------------------------------------------
extern "C" void kernel_launch(void* const* d_in, const int* in_sizes, int n_in,
                              void* d_out, int out_size, void* d_ws, size_t ws_size,
                              hipStream_t stream) {
    const float* x_in = (const float*)d_in[0];
    const float* ln1 = (const float*)d_in[2];
    const float* ln2 = (const float*)d_in[3];
    const float* q_w = (const float*)d_in[4];  const float* q_b = (const float*)d_in[5];
    const float* k_w = (const float*)d_in[6];  const float* k_b = (const float*)d_in[7];
    const float* v_w = (const float*)d_in[8];  const float* v_b = (const float*)d_in[9];
    const float* o_w = (const float*)d_in[10]; const float* o_b = (const float*)d_in[11];
    const float* g_w = (const float*)d_in[12]; const float* g_b = (const float*)d_in[13];
    const float* u_w = (const float*)d_in[14]; const float* u_b = (const float*)d_in[15];
    const float* dn_w = (const float*)d_in[16]; const float* dn_b = (const float*)d_in[17];
    const int* pos = (const int*)d_in[18];
    float* out = (float*)d_out;

    const size_t SZ_WBUF = (size_t)INTER * H * 2;       // 90,177,536
    const size_t SZ_H    = (size_t)S * H * 2;           // 16,777,216
    const size_t SZ_SH4  = (size_t)S * H * 4;           // 33,554,432
    const size_t SZ_B    = (size_t)S * INTER * 4;       // 90,177,536
    const size_t OFF_H   = SZ_WBUF;
    const size_t OFF_B   = OFF_H + SZ_H;
    const size_t OFF_C   = OFF_B + SZ_B;
    const size_t OFF_TAB = OFF_C + 6 * SZ_H;
    if (ws_size < OFF_TAB + (size_t)S * 128 * 4) return;

    char* ws = (char*)d_ws;
    u16* wbuf   = (u16*)(ws);
    u16* h      = (u16*)(ws + OFF_H);
    // region B: q32+k32 -> ctx -> x2 (lifetimes disjoint)
    float* q32  = (float*)(ws + OFF_B);
    float* k32  = (float*)(ws + OFF_B + SZ_SH4);
    float* ctx  = (float*)(ws + OFF_B);
    float* x2   = (float*)(ws + OFF_B);
    // region C: q/k/v splits -> hid + act2
    u16* qh = (u16*)(ws + OFF_C);
    u16* ql = (u16*)(ws + OFF_C + SZ_H);
    u16* kh = (u16*)(ws + OFF_C + 2 * SZ_H);
    u16* kl = (u16*)(ws + OFF_C + 3 * SZ_H);
    u16* vh = (u16*)(ws + OFF_C + 4 * SZ_H);
    u16* vl = (u16*)(ws + OFF_C + 5 * SZ_H);
    float* hid = (float*)(ws + OFF_C);             // covers qh+ql (dead after attn)
    u16* act2  = (u16*)(ws + OFF_C + 3 * SZ_H);    // covers kl (dead after attn)
    float* tab = (float*)(ws + OFF_TAB);

    dim3 b256(256);
    const int HH4 = H * H / 4;          // 4,194,304
    const int IH4 = INTER * H / 4;      // 11,272,192

    rope_table<<<dim3(S), dim3(64), 0, stream>>>(pos, tab);
    rmsnorm_csm_quant<<<dim3(S), b256, 0, stream>>>(x_in, ln1, h);

    // Q
    cvt_f32_bf16<<<dim3(2048), b256, 0, stream>>>((const float4*)q_w, (ushort4*)wbuf, HH4);
    gemm_bt<0><<<dim3(16, 32), b256, 0, stream>>>(h, wbuf, q_b, 2e-5f, H, H, q32, nullptr, nullptr, nullptr);
    // K
    cvt_f32_bf16<<<dim3(2048), b256, 0, stream>>>((const float4*)k_w, (ushort4*)wbuf, HH4);
    gemm_bt<0><<<dim3(16, 32), b256, 0, stream>>>(h, wbuf, k_b, 2e-5f, H, H, k32, nullptr, nullptr, nullptr);
    // V (store hi/lo split bf16)
    cvt_f32_bf16<<<dim3(2048), b256, 0, stream>>>((const float4*)v_w, (ushort4*)wbuf, HH4);
    gemm_bt<1><<<dim3(16, 32), b256, 0, stream>>>(h, wbuf, v_b, 2e-5f, H, H, nullptr, vh, vl, nullptr);

    rope_apply<<<dim3(S * NH * 64 / 256), b256, 0, stream>>>(q32, k32, tab, qh, ql, kh, kl);
    attn<<<dim3(NH, S / 64), b256, 0, stream>>>(qh, ql, kh, kl, vh, vl, ctx);
    quant_to_bf16<<<dim3(2048), b256, 0, stream>>>((const float4*)ctx, (ushort4*)h, S * H / 4);

    // O proj + residual (hid overlaps dead qh/ql)
    cvt_f32_bf16<<<dim3(2048), b256, 0, stream>>>((const float4*)o_w, (ushort4*)wbuf, HH4);
    gemm_bt<2><<<dim3(16, 32), b256, 0, stream>>>(h, wbuf, o_b, 2e-4f, H, H, hid, nullptr, nullptr, x_in);

    rmsnorm_csm_quant<<<dim3(S), b256, 0, stream>>>(hid, ln2, h);

    // up
    cvt_f32_bf16<<<dim3(2048), b256, 0, stream>>>((const float4*)u_w, (ushort4*)wbuf, IH4);
    gemm_bt<0><<<dim3(16, 86), b256, 0, stream>>>(h, wbuf, u_b, 6e-5f, INTER, H, x2, nullptr, nullptr, nullptr);
    // gate (+ silu * up + quant)
    cvt_f32_bf16<<<dim3(2048), b256, 0, stream>>>((const float4*)g_w, (ushort4*)wbuf, IH4);
    gemm_bt<3><<<dim3(16, 86), b256, 0, stream>>>(h, wbuf, g_b, 6e-5f, INTER, H, nullptr, act2, nullptr, x2);
    // down + residual -> out
    cvt_f32_bf16<<<dim3(2048), b256, 0, stream>>>((const float4*)dn_w, (ushort4*)wbuf, IH4);
    gemm_bt<2><<<dim3(16, 32), b256, 0, stream>>>(act2, wbuf, dn_b, 2e-4f, H, INTER, out, nullptr, nullptr, hid);
}

// Round 2
// 2153.608 us; speedup vs baseline: 1.2185x; 1.0869x over previous
//
#include <hip/hip_runtime.h>
#include <hip/hip_bf16.h>
#include <math.h>

#define S 2048
#define H 4096
#define NH 32
#define HD 128
#define INTER 11008

typedef unsigned short u16;
typedef __attribute__((ext_vector_type(8))) short bf16x8;
typedef __attribute__((ext_vector_type(4))) float f32x4;

// round-to-nearest-even f32 -> bf16 (exact for ints |x| <= 256)
__device__ __forceinline__ u16 f2b(float f) {
    unsigned u = __float_as_uint(f);
    unsigned r = (u + 0x7fffu + ((u >> 16) & 1u)) >> 16;
    return (u16)r;
}
__device__ __forceinline__ float b2f(u16 u) {
    return __uint_as_float(((unsigned)u) << 16);
}
// split f32 into hi+lo bf16 (x ~= hi+lo to 2^-18 rel)
__device__ __forceinline__ void split2(float v, u16* hi, u16* lo) {
    u16 h = f2b(v);
    *hi = h;
    *lo = f2b(v - b2f(h));
}

__device__ __forceinline__ void gl_lds16(const void* g, void* l) {
    __builtin_amdgcn_global_load_lds((const __attribute__((address_space(1))) void*)g,
                                     (__attribute__((address_space(3))) void*)l, 16, 0, 0);
}

// granule swizzle for 128B-stride LDS tiles (attn V/P)
__device__ __forceinline__ int swz8(int r) { return (r ^ (r >> 3)) & 7; }

// ---------------- rmsnorm + CSM gather + quant -> bf16 int values ----------
__global__ __launch_bounds__(256)
void rmsnorm_csm_quant(const float* __restrict__ x, const float* __restrict__ w,
                       u16* __restrict__ out) {
    const int s = blockIdx.x, tid = threadIdx.x;
    const float* xr = x + (size_t)s * H;
    float ss = 0.f;
#pragma unroll
    for (int i = 0; i < 16; ++i) { float v = xr[tid + i * 256]; ss += v * v; }
#pragma unroll
    for (int off = 32; off >= 1; off >>= 1) ss += __shfl_xor(ss, off, 64);
    __shared__ float red[4];
    if ((tid & 63) == 0) red[tid >> 6] = ss;
    __syncthreads();
    float tot = red[0] + red[1] + red[2] + red[3];
    float scale = 1.0f / sqrtf(tot * (1.0f / H) + 1e-6f);
    u16* orow = out + (size_t)s * H;
#pragma unroll
    for (int i = 0; i < 16; ++i) {
        int j = tid + i * 256;
        int src = (j <= 19) ? 0 : ((j <= 38) ? (2 * j - 38) : j);
        float v = xr[src] * scale * w[src];
        float qv = fminf(fmaxf(rintf(v), -128.f), 127.f);
        orow[j] = f2b(qv);
    }
}

// ---------------- f32 -> bf16 weight convert (values are small ints) -------
__global__ __launch_bounds__(256)
void cvt_f32_bf16(const float4* __restrict__ src, ushort4* __restrict__ dst, int n4) {
    for (int i = blockIdx.x * 256 + threadIdx.x; i < n4; i += gridDim.x * 256) {
        float4 v = src[i];
        ushort4 o;
        o.x = f2b(v.x); o.y = f2b(v.y); o.z = f2b(v.z); o.w = f2b(v.w);
        dst[i] = o;
    }
}

// ---------------- quantize f32 ctx -> int bf16 -----------------------------
__global__ __launch_bounds__(256)
void quant_to_bf16(const float4* __restrict__ src, ushort4* __restrict__ dst, int n4) {
    for (int i = blockIdx.x * 256 + threadIdx.x; i < n4; i += gridDim.x * 256) {
        float4 v = src[i];
        ushort4 o;
        o.x = f2b(fminf(fmaxf(rintf(v.x), -128.f), 127.f));
        o.y = f2b(fminf(fmaxf(rintf(v.y), -128.f), 127.f));
        o.z = f2b(fminf(fmaxf(rintf(v.z), -128.f), 127.f));
        o.w = f2b(fminf(fmaxf(rintf(v.w), -128.f), 127.f));
        dst[i] = o;
    }
}

// ---------------- rope table (f64 trig, 2048 x 64 pairs) -------------------
__global__ void rope_table(const int* __restrict__ pos, float* __restrict__ tab) {
    int s = blockIdx.x, i = threadIdx.x;  // block = 64 threads
    double inv = pow(10000.0, -(double)(2 * i) / 128.0);
    double ang = (double)pos[s] * inv;
    tab[s * 128 + 2 * i]     = (float)cos(ang);
    tab[s * 128 + 2 * i + 1] = (float)sin(ang);
}

// ---------------- apply rope, emit hi/lo split bf16 q/k --------------------
__global__ __launch_bounds__(256)
void rope_apply(const float* __restrict__ q32, const float* __restrict__ k32,
                const float* __restrict__ tab,
                u16* __restrict__ qh, u16* __restrict__ ql,
                u16* __restrict__ kh, u16* __restrict__ kl) {
    int idx = blockIdx.x * 256 + threadIdx.x;   // S*NH*64
    int s = idx >> 11;
    int hh = (idx >> 6) & 31;
    int i = idx & 63;
    size_t base = (size_t)s * H + hh * HD + i;
    float cs = tab[s * 128 + 2 * i], sn = tab[s * 128 + 2 * i + 1];
    float a = q32[base], b = q32[base + 64];
    split2(a * cs - b * sn, &qh[base], &ql[base]);
    split2(b * cs + a * sn, &qh[base + 64], &ql[base + 64]);
    float c = k32[base], d = k32[base + 64];
    split2(c * cs - d * sn, &kh[base], &kl[base]);
    split2(d * cs + c * sn, &kh[base + 64], &kl[base + 64]);
}

// ---------------- GEMM: C[m,n] = alpha * sum_k A[m,k]*B[n,k] + bias[n] -----
// A: [2048][K] bf16, B: [N][K] bf16 (both K-contiguous). 128x128 tile, BK=64.
// v2: double-buffered LDS, ONE barrier per K-step (next-tile global_load_lds
//     issued before compute; barrier's implicit vmcnt(0) drain makes it safe);
//     granule-XOR LDS swizzle (pre-swizzled global source, rule both-sides);
//     T1 bijective XCD blockIdx swizzle (requires gridDim.x==16, nwg%8==0).
// EPI: 0 = store f32; 1 = store hi/lo split bf16 (outb,outb2); 2 = f32 +
//      extra (residual); 3 = gate (silu(val) * extra, quantize, store bf16)
template <int EPI>
__global__ __launch_bounds__(256)
void gemm_bt(const u16* __restrict__ A, const u16* __restrict__ B,
             const float* __restrict__ bias, float alpha, int N, int K,
             float* __restrict__ outf, u16* __restrict__ outb,
             u16* __restrict__ outb2, const float* __restrict__ extra) {
    __shared__ u16 As[2][128 * 64];
    __shared__ u16 Bs[2][128 * 64];
    const int tid = threadIdx.x;
    const int wave = tid >> 6, lane = tid & 63;
    // T1 XCD swizzle (gridDim.x == 16 always; nwg % 8 == 0 always)
    const int nwg = (int)(gridDim.x * gridDim.y);
    const int bid = (int)(blockIdx.y * gridDim.x + blockIdx.x);
    const int wg = (bid & 7) * (nwg >> 3) + (bid >> 3);
    const int mb = wg & 15, nb = wg >> 4;
    const int waveM = wave & 1, waveN = wave >> 1;
    const int m0 = mb * 128, n0 = nb * 128;
    const int lrow = lane >> 3;              // row within 8-row chunk
    const int lg = lane & 7;                 // granule slot
    const int lk8 = (lg ^ lrow) * 8;         // T2: pre-swizzled source granule
    const int q = lane >> 4, c = lane & 15;
    const int c7 = c & 7;
    f32x4 acc[4][4] = {};
    const int nk = K >> 6;
    // prologue: stage tile 0 into buf 0
#pragma unroll
    for (int i = 0; i < 4; ++i) {
        int ch = wave * 4 + i;
        gl_lds16(A + (size_t)(m0 + ch * 8 + lrow) * K + lk8,
                 (void*)((char*)As[0] + ch * 1024));
        gl_lds16(B + (size_t)(n0 + ch * 8 + lrow) * K + lk8,
                 (void*)((char*)Bs[0] + ch * 1024));
    }
    __syncthreads();
    for (int t = 0; t < nk; ++t) {
        const int cur = t & 1;
        if (t + 1 < nk) {
            const int k0 = (t + 1) << 6;
#pragma unroll
            for (int i = 0; i < 4; ++i) {
                int ch = wave * 4 + i;
                gl_lds16(A + (size_t)(m0 + ch * 8 + lrow) * K + k0 + lk8,
                         (void*)((char*)As[cur ^ 1] + ch * 1024));
                gl_lds16(B + (size_t)(n0 + ch * 8 + lrow) * K + k0 + lk8,
                         (void*)((char*)Bs[cur ^ 1] + ch * 1024));
            }
        }
#pragma unroll
        for (int kk = 0; kk < 2; ++kk) {
            bf16x8 af[4], bff[4];
#pragma unroll
            for (int t4 = 0; t4 < 4; ++t4)
                af[t4] = *(const bf16x8*)&As[cur][(waveM * 64 + t4 * 16 + c) * 64 +
                                                  (((kk * 4 + q) ^ c7) << 3)];
#pragma unroll
            for (int t4 = 0; t4 < 4; ++t4)
                bff[t4] = *(const bf16x8*)&Bs[cur][(waveN * 64 + t4 * 16 + c) * 64 +
                                                   (((kk * 4 + q) ^ c7) << 3)];
#pragma unroll
            for (int im = 0; im < 4; ++im)
#pragma unroll
                for (int in = 0; in < 4; ++in)
                    acc[im][in] = __builtin_amdgcn_mfma_f32_16x16x32_bf16(
                        af[im], bff[in], acc[im][in], 0, 0, 0);
        }
        __syncthreads();
    }
#pragma unroll
    for (int im = 0; im < 4; ++im) {
#pragma unroll
        for (int in = 0; in < 4; ++in) {
#pragma unroll
            for (int r = 0; r < 4; ++r) {
                int row = m0 + waveM * 64 + im * 16 + q * 4 + r;
                int col = n0 + waveN * 64 + in * 16 + c;
                float val = acc[im][in][r] * alpha + bias[col];
                size_t o = (size_t)row * N + col;
                if (EPI == 0) {
                    outf[o] = val;
                } else if (EPI == 1) {
                    split2(val, &outb[o], &outb2[o]);
                } else if (EPI == 2) {
                    outf[o] = val + extra[o];
                } else {
                    float x1 = val / (1.f + __expf(-val));
                    float p = x1 * extra[o];
                    float qv = fminf(fmaxf(rintf(p), -128.f), 127.f);
                    outb[o] = f2b(qv);
                }
            }
        }
    }
}

// ---------------- flash attention, split-bf16 (emulated fp32) MFMA ---------
// grid 1024 flat; block 256 = 4 waves; wave w owns q rows qb*64+w*16 .. +15
// Block remap: XCD-bijective swizzle clusters 4 heads per XCD (KV L2 reuse)
// and REVERSES qb so the longest causal blocks (32 tiles) launch first.
// LDS swizzles as in v1 (K: src-granule ^ row; V/P: swz8 on key granule).
__global__ __launch_bounds__(256)
void attn(const u16* __restrict__ Qh, const u16* __restrict__ Ql,
          const u16* __restrict__ Kh, const u16* __restrict__ Kl,
          const u16* __restrict__ Vh, const u16* __restrict__ Vl,
          float* __restrict__ ctx) {
    __shared__ u16 Ksh[64 * 128];   // [key][d]   (granule-swizzled)
    __shared__ u16 Ksl[64 * 128];
    __shared__ u16 Vth[128 * 64];   // [d][key]   (granule-swizzled)
    __shared__ u16 Vtl[128 * 64];
    __shared__ u16 Psh[4][16 * 64]; // per-wave P, A-layout [m][key] (swizzled)
    __shared__ u16 Psl[4][16 * 64];
    const int bid = blockIdx.x;
    const int wg = (bid & 7) * 128 + (bid >> 3);   // 1024 % 8 == 0, bijective
    const int hh = wg >> 5;
    const int qb = 31 - (wg & 31);                 // long blocks first
    const int tid = threadIdx.x, wave = tid >> 6, lane = tid & 63;
    const int quad = lane >> 4, c = lane & 15;
    const int q0w = qb * 64 + wave * 16;
    const int swzc = swz8(c);

    bf16x8 qfh[4], qfl[4];
#pragma unroll
    for (int ks = 0; ks < 4; ++ks) {
        size_t o = (size_t)(q0w + c) * H + hh * HD + ks * 32 + quad * 8;
        qfh[ks] = *(const bf16x8*)(Qh + o);
        qfl[ks] = *(const bf16x8*)(Ql + o);
    }

    f32x4 oacc[8] = {};
    float mi[4], li[4];
#pragma unroll
    for (int r = 0; r < 4; ++r) { mi[r] = -1e30f; li[r] = 0.f; }

    const int ntiles = qb + 1;
    for (int kt = 0; kt < ntiles; ++kt) {
        const int k0 = kt * 64;
        // stage K hi/lo tiles via global_load_lds (linear dest, swizzled src)
#pragma unroll
        for (int i2 = 0; i2 < 4; ++i2) {
            int ch = wave * 4 + i2;
            int krow = ch * 4 + quad;
            int cs = c ^ (krow & 15);
            size_t go = (size_t)(k0 + krow) * H + hh * HD + cs * 8;
            gl_lds16(Kh + go, (void*)((char*)Ksh + ch * 1024));
            gl_lds16(Kl + go, (void*)((char*)Ksl + ch * 1024));
        }
        // stage V hi/lo transposed: Vt[d][key], key-granule swizzled by swz8(d)
#pragma unroll
        for (int i2 = 0; i2 < 4; ++i2) {
            int cc = i2 * 256 + tid;
            int key = cc >> 4, dg = cc & 15;
            size_t go = (size_t)(k0 + key) * H + hh * HD + dg * 8;
            uint4 hv = *(const uint4*)(Vh + go);
            uint4 lv = *(const uint4*)(Vl + go);
            u16 eh[8], el[8];
            *(uint4*)eh = hv;
            *(uint4*)el = lv;
#pragma unroll
            for (int j = 0; j < 8; ++j) {
                int vrow = dg * 8 + j;
                int col = key ^ (swz8(vrow) << 3);
                Vth[vrow * 64 + col] = eh[j];
                Vtl[vrow * 64 + col] = el[j];
            }
        }
        __syncthreads();
        // scores: sc = qh*kh + qh*kl + ql*kh   (emulated fp32)
        f32x4 sc[4] = {};
#pragma unroll
        for (int ks = 0; ks < 4; ++ks) {
#pragma unroll
            for (int nt = 0; nt < 4; ++nt) {
                int ko = (nt * 16 + c) * 128 + (((ks * 4 + quad) ^ c) * 8);
                bf16x8 kfh = *(const bf16x8*)&Ksh[ko];
                bf16x8 kfl = *(const bf16x8*)&Ksl[ko];
                sc[nt] = __builtin_amdgcn_mfma_f32_16x16x32_bf16(qfh[ks], kfh, sc[nt], 0, 0, 0);
                sc[nt] = __builtin_amdgcn_mfma_f32_16x16x32_bf16(qfh[ks], kfl, sc[nt], 0, 0, 0);
                sc[nt] = __builtin_amdgcn_mfma_f32_16x16x32_bf16(qfl[ks], kfh, sc[nt], 0, 0, 0);
            }
        }
        // scale + causal mask
#pragma unroll
        for (int nt = 0; nt < 4; ++nt)
#pragma unroll
            for (int r = 0; r < 4; ++r) {
                float v = sc[nt][r] * 0.08838834764831845f;
                int key = k0 + nt * 16 + c, qrow = q0w + quad * 4 + r;
                sc[nt][r] = (key > qrow) ? -1e30f : v;
            }
        // online softmax
#pragma unroll
        for (int r = 0; r < 4; ++r) {
            float mx = fmaxf(fmaxf(sc[0][r], sc[1][r]), fmaxf(sc[2][r], sc[3][r]));
#pragma unroll
            for (int off = 8; off >= 1; off >>= 1) mx = fmaxf(mx, __shfl_xor(mx, off, 64));
            float mnew = fmaxf(mi[r], mx);
            float al = __expf(mi[r] - mnew);
            float rs = 0.f;
#pragma unroll
            for (int nt = 0; nt < 4; ++nt) {
                float p = __expf(sc[nt][r] - mnew);
                sc[nt][r] = p;
                rs += p;
            }
#pragma unroll
            for (int off = 8; off >= 1; off >>= 1) rs += __shfl_xor(rs, off, 64);
            li[r] = li[r] * al + rs;
            mi[r] = mnew;
#pragma unroll
            for (int dt = 0; dt < 8; ++dt) oacc[dt][r] *= al;
        }
        // P -> LDS hi/lo (A-operand layout, granule-swizzled)
#pragma unroll
        for (int nt = 0; nt < 4; ++nt)
#pragma unroll
            for (int r = 0; r < 4; ++r) {
                int prow = quad * 4 + r;
                int o = prow * 64 + ((nt * 16 + c) ^ (swz8(prow) << 3));
                split2(sc[nt][r], &Psh[wave][o], &Psl[wave][o]);
            }
        __syncthreads();
        // PV: oacc += ph*vh + ph*vl + pl*vh
#pragma unroll
        for (int ks2 = 0; ks2 < 2; ++ks2) {
            int po = c * 64 + (((ks2 * 4 + quad) ^ swzc) * 8);
            bf16x8 pfh = *(const bf16x8*)&Psh[wave][po];
            bf16x8 pfl = *(const bf16x8*)&Psl[wave][po];
#pragma unroll
            for (int dt = 0; dt < 8; ++dt) {
                int vrow = dt * 16 + c;
                int vo = vrow * 64 + (((ks2 * 4 + quad) ^ swz8(vrow)) * 8);
                bf16x8 vfh = *(const bf16x8*)&Vth[vo];
                bf16x8 vfl = *(const bf16x8*)&Vtl[vo];
                oacc[dt] = __builtin_amdgcn_mfma_f32_16x16x32_bf16(pfh, vfh, oacc[dt], 0, 0, 0);
                oacc[dt] = __builtin_amdgcn_mfma_f32_16x16x32_bf16(pfh, vfl, oacc[dt], 0, 0, 0);
                oacc[dt] = __builtin_amdgcn_mfma_f32_16x16x32_bf16(pfl, vfh, oacc[dt], 0, 0, 0);
            }
        }
        __syncthreads();
    }
#pragma unroll
    for (int dt = 0; dt < 8; ++dt)
#pragma unroll
        for (int r = 0; r < 4; ++r)
            ctx[(size_t)(q0w + quad * 4 + r) * H + hh * HD + dt * 16 + c] =
                oacc[dt][r] / li[r];
}

// ---------------- host ------------------------------------------------------
extern "C" void kernel_launch(void* const* d_in, const int* in_sizes, int n_in,
                              void* d_out, int out_size, void* d_ws, size_t ws_size,
                              hipStream_t stream) {
    const float* x_in = (const float*)d_in[0];
    const float* ln1 = (const float*)d_in[2];
    const float* ln2 = (const float*)d_in[3];
    const float* q_w = (const float*)d_in[4];  const float* q_b = (const float*)d_in[5];
    const float* k_w = (const float*)d_in[6];  const float* k_b = (const float*)d_in[7];
    const float* v_w = (const float*)d_in[8];  const float* v_b = (const float*)d_in[9];
    const float* o_w = (const float*)d_in[10]; const float* o_b = (const float*)d_in[11];
    const float* g_w = (const float*)d_in[12]; const float* g_b = (const float*)d_in[13];
    const float* u_w = (const float*)d_in[14]; const float* u_b = (const float*)d_in[15];
    const float* dn_w = (const float*)d_in[16]; const float* dn_b = (const float*)d_in[17];
    const int* pos = (const int*)d_in[18];
    float* out = (float*)d_out;

    const size_t SZ_WBUF = (size_t)INTER * H * 2;       // 90,177,536
    const size_t SZ_H    = (size_t)S * H * 2;           // 16,777,216
    const size_t SZ_SH4  = (size_t)S * H * 4;           // 33,554,432
    const size_t SZ_B    = (size_t)S * INTER * 4;       // 90,177,536
    const size_t OFF_H   = SZ_WBUF;
    const size_t OFF_B   = OFF_H + SZ_H;
    const size_t OFF_C   = OFF_B + SZ_B;
    const size_t OFF_TAB = OFF_C + 6 * SZ_H;
    if (ws_size < OFF_TAB + (size_t)S * 128 * 4) return;

    char* ws = (char*)d_ws;
    u16* wbuf   = (u16*)(ws);
    u16* h      = (u16*)(ws + OFF_H);
    // region B: q32+k32 -> ctx -> x2 (lifetimes disjoint)
    float* q32  = (float*)(ws + OFF_B);
    float* k32  = (float*)(ws + OFF_B + SZ_SH4);
    float* ctx  = (float*)(ws + OFF_B);
    float* x2   = (float*)(ws + OFF_B);
    // region C: q/k/v splits -> hid + act2
    u16* qh = (u16*)(ws + OFF_C);
    u16* ql = (u16*)(ws + OFF_C + SZ_H);
    u16* kh = (u16*)(ws + OFF_C + 2 * SZ_H);
    u16* kl = (u16*)(ws + OFF_C + 3 * SZ_H);
    u16* vh = (u16*)(ws + OFF_C + 4 * SZ_H);
    u16* vl = (u16*)(ws + OFF_C + 5 * SZ_H);
    float* hid = (float*)(ws + OFF_C);             // covers qh+ql (dead after attn)
    u16* act2  = (u16*)(ws + OFF_C + 3 * SZ_H);    // covers kl (dead after attn)
    float* tab = (float*)(ws + OFF_TAB);

    dim3 b256(256);
    const int HH4 = H * H / 4;          // 4,194,304
    const int IH4 = INTER * H / 4;      // 11,272,192

    rope_table<<<dim3(S), dim3(64), 0, stream>>>(pos, tab);
    rmsnorm_csm_quant<<<dim3(S), b256, 0, stream>>>(x_in, ln1, h);

    // Q
    cvt_f32_bf16<<<dim3(2048), b256, 0, stream>>>((const float4*)q_w, (ushort4*)wbuf, HH4);
    gemm_bt<0><<<dim3(16, 32), b256, 0, stream>>>(h, wbuf, q_b, 2e-5f, H, H, q32, nullptr, nullptr, nullptr);
    // K
    cvt_f32_bf16<<<dim3(2048), b256, 0, stream>>>((const float4*)k_w, (ushort4*)wbuf, HH4);
    gemm_bt<0><<<dim3(16, 32), b256, 0, stream>>>(h, wbuf, k_b, 2e-5f, H, H, k32, nullptr, nullptr, nullptr);
    // V (store hi/lo split bf16)
    cvt_f32_bf16<<<dim3(2048), b256, 0, stream>>>((const float4*)v_w, (ushort4*)wbuf, HH4);
    gemm_bt<1><<<dim3(16, 32), b256, 0, stream>>>(h, wbuf, v_b, 2e-5f, H, H, nullptr, vh, vl, nullptr);

    rope_apply<<<dim3(S * NH * 64 / 256), b256, 0, stream>>>(q32, k32, tab, qh, ql, kh, kl);
    attn<<<dim3(NH * S / 64), b256, 0, stream>>>(qh, ql, kh, kl, vh, vl, ctx);
    quant_to_bf16<<<dim3(2048), b256, 0, stream>>>((const float4*)ctx, (ushort4*)h, S * H / 4);

    // O proj + residual (hid overlaps dead qh/ql)
    cvt_f32_bf16<<<dim3(2048), b256, 0, stream>>>((const float4*)o_w, (ushort4*)wbuf, HH4);
    gemm_bt<2><<<dim3(16, 32), b256, 0, stream>>>(h, wbuf, o_b, 2e-4f, H, H, hid, nullptr, nullptr, x_in);

    rmsnorm_csm_quant<<<dim3(S), b256, 0, stream>>>(hid, ln2, h);

    // up
    cvt_f32_bf16<<<dim3(2048), b256, 0, stream>>>((const float4*)u_w, (ushort4*)wbuf, IH4);
    gemm_bt<0><<<dim3(16, 86), b256, 0, stream>>>(h, wbuf, u_b, 6e-5f, INTER, H, x2, nullptr, nullptr, nullptr);
    // gate (+ silu * up + quant)
    cvt_f32_bf16<<<dim3(2048), b256, 0, stream>>>((const float4*)g_w, (ushort4*)wbuf, IH4);
    gemm_bt<3><<<dim3(16, 86), b256, 0, stream>>>(h, wbuf, g_b, 6e-5f, INTER, H, nullptr, act2, nullptr, x2);
    // down + residual -> out
    cvt_f32_bf16<<<dim3(2048), b256, 0, stream>>>((const float4*)dn_w, (ushort4*)wbuf, IH4);
    gemm_bt<2><<<dim3(16, 32), b256, 0, stream>>>(act2, wbuf, dn_b, 2e-4f, H, INTER, out, nullptr, nullptr, hid);
}

// Round 3
// 1686.912 us; speedup vs baseline: 1.5556x; 1.2767x over previous
//
#include <hip/hip_runtime.h>
#include <hip/hip_bf16.h>
#include <math.h>

#define S 2048
#define H 4096
#define NH 32
#define HD 128
#define INTER 11008

typedef unsigned short u16;
typedef signed char i8;
typedef __attribute__((ext_vector_type(8))) short bf16x8;
typedef __attribute__((ext_vector_type(4))) float f32x4;
typedef __attribute__((ext_vector_type(4))) int i32x4;

// round-to-nearest-even f32 -> bf16 (exact for ints |x| <= 256)
__device__ __forceinline__ u16 f2b(float f) {
    unsigned u = __float_as_uint(f);
    unsigned r = (u + 0x7fffu + ((u >> 16) & 1u)) >> 16;
    return (u16)r;
}
__device__ __forceinline__ float b2f(u16 u) {
    return __uint_as_float(((unsigned)u) << 16);
}
// split f32 into hi+lo bf16 (x ~= hi+lo to 2^-18 rel)
__device__ __forceinline__ void split2(float v, u16* hi, u16* lo) {
    u16 h = f2b(v);
    *hi = h;
    *lo = f2b(v - b2f(h));
}

__device__ __forceinline__ void gl_lds16(const void* g, void* l) {
    __builtin_amdgcn_global_load_lds((const __attribute__((address_space(1))) void*)g,
                                     (__attribute__((address_space(3))) void*)l, 16, 0, 0);
}

// granule swizzle for 128B-stride LDS tiles (attn V/P)
__device__ __forceinline__ int swz8(int r) { return (r ^ (r >> 3)) & 7; }
// granule swizzle for 64B-stride i8 tiles (4 granules/row)
__device__ __forceinline__ int f4(int r) { return (r & 3) ^ ((r >> 2) & 3); }

// ---------------- rmsnorm + CSM gather + quant -> i8 -----------------------
__global__ __launch_bounds__(256)
void rmsnorm_csm_quant(const float* __restrict__ x, const float* __restrict__ w,
                       i8* __restrict__ out) {
    const int s = blockIdx.x, tid = threadIdx.x;
    const float* xr = x + (size_t)s * H;
    float ss = 0.f;
#pragma unroll
    for (int i = 0; i < 16; ++i) { float v = xr[tid + i * 256]; ss += v * v; }
#pragma unroll
    for (int off = 32; off >= 1; off >>= 1) ss += __shfl_xor(ss, off, 64);
    __shared__ float red[4];
    if ((tid & 63) == 0) red[tid >> 6] = ss;
    __syncthreads();
    float tot = red[0] + red[1] + red[2] + red[3];
    float scale = 1.0f / sqrtf(tot * (1.0f / H) + 1e-6f);
    i8* orow = out + (size_t)s * H;
#pragma unroll
    for (int i = 0; i < 16; ++i) {
        int j = tid + i * 256;
        int src = (j <= 19) ? 0 : ((j <= 38) ? (2 * j - 38) : j);
        float v = xr[src] * scale * w[src];
        float qv = fminf(fmaxf(rintf(v), -128.f), 127.f);
        orow[j] = (i8)(int)qv;
    }
}

// ---------------- f32 -> i8 weight convert (values are exact small ints) ---
__global__ __launch_bounds__(256)
void cvt_f32_i8(const float4* __restrict__ src, uint2* __restrict__ dst, int n8) {
    for (int i = blockIdx.x * 256 + threadIdx.x; i < n8; i += gridDim.x * 256) {
        float4 a = src[2 * i], b = src[2 * i + 1];
        unsigned lo = ((unsigned)(unsigned char)(int)a.x) |
                      ((unsigned)(unsigned char)(int)a.y << 8) |
                      ((unsigned)(unsigned char)(int)a.z << 16) |
                      ((unsigned)(unsigned char)(int)a.w << 24);
        unsigned hi = ((unsigned)(unsigned char)(int)b.x) |
                      ((unsigned)(unsigned char)(int)b.y << 8) |
                      ((unsigned)(unsigned char)(int)b.z << 16) |
                      ((unsigned)(unsigned char)(int)b.w << 24);
        uint2 o; o.x = lo; o.y = hi;
        dst[i] = o;
    }
}

// ---------------- quantize f32 ctx -> i8 -----------------------------------
__global__ __launch_bounds__(256)
void quant_to_i8(const float4* __restrict__ src, unsigned* __restrict__ dst, int n4) {
    for (int i = blockIdx.x * 256 + threadIdx.x; i < n4; i += gridDim.x * 256) {
        float4 v = src[i];
        float q0 = fminf(fmaxf(rintf(v.x), -128.f), 127.f);
        float q1 = fminf(fmaxf(rintf(v.y), -128.f), 127.f);
        float q2 = fminf(fmaxf(rintf(v.z), -128.f), 127.f);
        float q3 = fminf(fmaxf(rintf(v.w), -128.f), 127.f);
        dst[i] = ((unsigned)(unsigned char)(int)q0) |
                 ((unsigned)(unsigned char)(int)q1 << 8) |
                 ((unsigned)(unsigned char)(int)q2 << 16) |
                 ((unsigned)(unsigned char)(int)q3 << 24);
    }
}

// ---------------- rope table (f64 trig, 2048 x 64 pairs) -------------------
__global__ void rope_table(const int* __restrict__ pos, float* __restrict__ tab) {
    int s = blockIdx.x, i = threadIdx.x;  // block = 64 threads
    double inv = pow(10000.0, -(double)(2 * i) / 128.0);
    double ang = (double)pos[s] * inv;
    tab[s * 128 + 2 * i]     = (float)cos(ang);
    tab[s * 128 + 2 * i + 1] = (float)sin(ang);
}

// ---------------- apply rope, emit hi/lo split bf16 q/k --------------------
__global__ __launch_bounds__(256)
void rope_apply(const float* __restrict__ q32, const float* __restrict__ k32,
                const float* __restrict__ tab,
                u16* __restrict__ qh, u16* __restrict__ ql,
                u16* __restrict__ kh, u16* __restrict__ kl) {
    int idx = blockIdx.x * 256 + threadIdx.x;   // S*NH*64
    int s = idx >> 11;
    int hh = (idx >> 6) & 31;
    int i = idx & 63;
    size_t base = (size_t)s * H + hh * HD + i;
    float cs = tab[s * 128 + 2 * i], sn = tab[s * 128 + 2 * i + 1];
    float a = q32[base], b = q32[base + 64];
    split2(a * cs - b * sn, &qh[base], &ql[base]);
    split2(b * cs + a * sn, &qh[base + 64], &ql[base + 64]);
    float c = k32[base], d = k32[base + 64];
    split2(c * cs - d * sn, &kh[base], &kl[base]);
    split2(d * cs + c * sn, &kh[base + 64], &kl[base + 64]);
}

// ---------------- i8 GEMM: C[m,n] = alpha * sum_k A[m,k]*B[n,k] + bias[n] --
// A: [2048][K] i8, B: [N][K] i8 (both K-contiguous, K%64==0). 128x128 tile,
// BK=64, i32 accumulation via v_mfma_i32_16x16x64_i8 (exact).
// Double-buffered LDS, ONE barrier per K-step (next-tile global_load_lds
// issued before compute); granule-XOR swizzle g^=f4(row) with pre-swizzled
// global source (linear LDS dest); T1 bijective XCD swizzle (gridDim.x==16).
// EPI: 0 = store f32; 1 = store hi/lo split bf16 (outb,outb2); 2 = f32 +
//      extra (residual); 3 = gate (silu(val) * extra, quantize, store i8)
template <int EPI>
__global__ __launch_bounds__(256)
void gemm_i8(const i8* __restrict__ A, const i8* __restrict__ B,
             const float* __restrict__ bias, float alpha, int N, int K,
             float* __restrict__ outf, u16* __restrict__ outb,
             u16* __restrict__ outb2, i8* __restrict__ outc,
             const float* __restrict__ extra) {
    __shared__ i8 As[2][128 * 64];
    __shared__ i8 Bs[2][128 * 64];
    const int tid = threadIdx.x;
    const int wave = tid >> 6, lane = tid & 63;
    // T1 XCD swizzle (gridDim.x == 16 always; nwg % 8 == 0 always)
    const int nwg = (int)(gridDim.x * gridDim.y);
    const int bid = (int)(blockIdx.y * gridDim.x + blockIdx.x);
    const int wg = (bid & 7) * (nwg >> 3) + (bid >> 3);
    const int mb = wg & 15, nb = wg >> 4;
    const int waveM = wave & 1, waveN = wave >> 1;
    const int m0 = mb * 128, n0 = nb * 128;
    const int srow = lane >> 2;               // row 0..15 within 16-row chunk
    const int sg16 = ((lane & 3) ^ f4(srow)) * 16;  // pre-swizzled src granule
    const int q = lane >> 4, c = lane & 15;
    const int f4c = f4(c);
    i32x4 acc[4][4] = {};
    const int nk = K >> 6;
    // prologue: stage tile 0 into buf 0 (2 chunks of 16 rows per wave, A & B)
#pragma unroll
    for (int i = 0; i < 2; ++i) {
        int ch = wave * 2 + i;
        gl_lds16(A + (size_t)(m0 + ch * 16 + srow) * K + sg16,
                 (void*)((char*)As[0] + ch * 1024));
        gl_lds16(B + (size_t)(n0 + ch * 16 + srow) * K + sg16,
                 (void*)((char*)Bs[0] + ch * 1024));
    }
    __syncthreads();
    for (int t = 0; t < nk; ++t) {
        const int cur = t & 1;
        if (t + 1 < nk) {
            const int k0 = (t + 1) << 6;
#pragma unroll
            for (int i = 0; i < 2; ++i) {
                int ch = wave * 2 + i;
                gl_lds16(A + (size_t)(m0 + ch * 16 + srow) * K + k0 + sg16,
                         (void*)((char*)As[cur ^ 1] + ch * 1024));
                gl_lds16(B + (size_t)(n0 + ch * 16 + srow) * K + k0 + sg16,
                         (void*)((char*)Bs[cur ^ 1] + ch * 1024));
            }
        }
        {
            i32x4 af[4], bff[4];
#pragma unroll
            for (int t4 = 0; t4 < 4; ++t4)
                af[t4] = *(const i32x4*)&As[cur][(waveM * 64 + t4 * 16 + c) * 64 +
                                                 ((q ^ f4c) << 4)];
#pragma unroll
            for (int t4 = 0; t4 < 4; ++t4)
                bff[t4] = *(const i32x4*)&Bs[cur][(waveN * 64 + t4 * 16 + c) * 64 +
                                                  ((q ^ f4c) << 4)];
#pragma unroll
            for (int im = 0; im < 4; ++im)
#pragma unroll
                for (int in = 0; in < 4; ++in)
                    acc[im][in] = __builtin_amdgcn_mfma_i32_16x16x64_i8(
                        af[im], bff[in], acc[im][in], 0, 0, 0);
        }
        __syncthreads();
    }
#pragma unroll
    for (int im = 0; im < 4; ++im) {
#pragma unroll
        for (int in = 0; in < 4; ++in) {
#pragma unroll
            for (int r = 0; r < 4; ++r) {
                int row = m0 + waveM * 64 + im * 16 + q * 4 + r;
                int col = n0 + waveN * 64 + in * 16 + c;
                float val = (float)acc[im][in][r] * alpha + bias[col];
                size_t o = (size_t)row * N + col;
                if (EPI == 0) {
                    outf[o] = val;
                } else if (EPI == 1) {
                    split2(val, &outb[o], &outb2[o]);
                } else if (EPI == 2) {
                    outf[o] = val + extra[o];
                } else {
                    float x1 = val / (1.f + __expf(-val));
                    float p = x1 * extra[o];
                    float qv = fminf(fmaxf(rintf(p), -128.f), 127.f);
                    outc[o] = (i8)(int)qv;
                }
            }
        }
    }
}

// ---------------- flash attention, split-bf16 (emulated fp32) MFMA ---------
// grid (NH, S/64); block 256 = 4 waves; wave w owns q rows qb*64+w*16 .. +15
// (round-1 measured config: 2D grid, natural dispatch order)
__global__ __launch_bounds__(256)
void attn(const u16* __restrict__ Qh, const u16* __restrict__ Ql,
          const u16* __restrict__ Kh, const u16* __restrict__ Kl,
          const u16* __restrict__ Vh, const u16* __restrict__ Vl,
          float* __restrict__ ctx) {
    __shared__ u16 Ksh[64 * 128];   // [key][d]   (granule-swizzled)
    __shared__ u16 Ksl[64 * 128];
    __shared__ u16 Vth[128 * 64];   // [d][key]   (granule-swizzled)
    __shared__ u16 Vtl[128 * 64];
    __shared__ u16 Psh[4][16 * 64]; // per-wave P, A-layout [m][key] (swizzled)
    __shared__ u16 Psl[4][16 * 64];
    const int hh = blockIdx.x, qb = blockIdx.y;
    const int tid = threadIdx.x, wave = tid >> 6, lane = tid & 63;
    const int quad = lane >> 4, c = lane & 15;
    const int q0w = qb * 64 + wave * 16;
    const int swzc = swz8(c);

    bf16x8 qfh[4], qfl[4];
#pragma unroll
    for (int ks = 0; ks < 4; ++ks) {
        size_t o = (size_t)(q0w + c) * H + hh * HD + ks * 32 + quad * 8;
        qfh[ks] = *(const bf16x8*)(Qh + o);
        qfl[ks] = *(const bf16x8*)(Ql + o);
    }

    f32x4 oacc[8] = {};
    float mi[4], li[4];
#pragma unroll
    for (int r = 0; r < 4; ++r) { mi[r] = -1e30f; li[r] = 0.f; }

    const int ntiles = qb + 1;
    for (int kt = 0; kt < ntiles; ++kt) {
        const int k0 = kt * 64;
        // stage K hi/lo tiles via global_load_lds (linear dest, swizzled src)
#pragma unroll
        for (int i2 = 0; i2 < 4; ++i2) {
            int ch = wave * 4 + i2;
            int krow = ch * 4 + quad;
            int cs = c ^ (krow & 15);
            size_t go = (size_t)(k0 + krow) * H + hh * HD + cs * 8;
            gl_lds16(Kh + go, (void*)((char*)Ksh + ch * 1024));
            gl_lds16(Kl + go, (void*)((char*)Ksl + ch * 1024));
        }
        // stage V hi/lo transposed: Vt[d][key], key-granule swizzled by swz8(d)
#pragma unroll
        for (int i2 = 0; i2 < 4; ++i2) {
            int cc = i2 * 256 + tid;
            int key = cc >> 4, dg = cc & 15;
            size_t go = (size_t)(k0 + key) * H + hh * HD + dg * 8;
            uint4 hv = *(const uint4*)(Vh + go);
            uint4 lv = *(const uint4*)(Vl + go);
            u16 eh[8], el[8];
            *(uint4*)eh = hv;
            *(uint4*)el = lv;
#pragma unroll
            for (int j = 0; j < 8; ++j) {
                int vrow = dg * 8 + j;
                int col = key ^ (swz8(vrow) << 3);
                Vth[vrow * 64 + col] = eh[j];
                Vtl[vrow * 64 + col] = el[j];
            }
        }
        __syncthreads();
        // scores: sc = qh*kh + qh*kl + ql*kh   (emulated fp32)
        f32x4 sc[4] = {};
#pragma unroll
        for (int ks = 0; ks < 4; ++ks) {
#pragma unroll
            for (int nt = 0; nt < 4; ++nt) {
                int ko = (nt * 16 + c) * 128 + (((ks * 4 + quad) ^ c) * 8);
                bf16x8 kfh = *(const bf16x8*)&Ksh[ko];
                bf16x8 kfl = *(const bf16x8*)&Ksl[ko];
                sc[nt] = __builtin_amdgcn_mfma_f32_16x16x32_bf16(qfh[ks], kfh, sc[nt], 0, 0, 0);
                sc[nt] = __builtin_amdgcn_mfma_f32_16x16x32_bf16(qfh[ks], kfl, sc[nt], 0, 0, 0);
                sc[nt] = __builtin_amdgcn_mfma_f32_16x16x32_bf16(qfl[ks], kfh, sc[nt], 0, 0, 0);
            }
        }
        // scale + causal mask
#pragma unroll
        for (int nt = 0; nt < 4; ++nt)
#pragma unroll
            for (int r = 0; r < 4; ++r) {
                float v = sc[nt][r] * 0.08838834764831845f;
                int key = k0 + nt * 16 + c, qrow = q0w + quad * 4 + r;
                sc[nt][r] = (key > qrow) ? -1e30f : v;
            }
        // online softmax
#pragma unroll
        for (int r = 0; r < 4; ++r) {
            float mx = fmaxf(fmaxf(sc[0][r], sc[1][r]), fmaxf(sc[2][r], sc[3][r]));
#pragma unroll
            for (int off = 8; off >= 1; off >>= 1) mx = fmaxf(mx, __shfl_xor(mx, off, 64));
            float mnew = fmaxf(mi[r], mx);
            float al = __expf(mi[r] - mnew);
            float rs = 0.f;
#pragma unroll
            for (int nt = 0; nt < 4; ++nt) {
                float p = __expf(sc[nt][r] - mnew);
                sc[nt][r] = p;
                rs += p;
            }
#pragma unroll
            for (int off = 8; off >= 1; off >>= 1) rs += __shfl_xor(rs, off, 64);
            li[r] = li[r] * al + rs;
            mi[r] = mnew;
#pragma unroll
            for (int dt = 0; dt < 8; ++dt) oacc[dt][r] *= al;
        }
        // P -> LDS hi/lo (A-operand layout, granule-swizzled)
#pragma unroll
        for (int nt = 0; nt < 4; ++nt)
#pragma unroll
            for (int r = 0; r < 4; ++r) {
                int prow = quad * 4 + r;
                int o = prow * 64 + ((nt * 16 + c) ^ (swz8(prow) << 3));
                split2(sc[nt][r], &Psh[wave][o], &Psl[wave][o]);
            }
        __syncthreads();
        // PV: oacc += ph*vh + ph*vl + pl*vh
#pragma unroll
        for (int ks2 = 0; ks2 < 2; ++ks2) {
            int po = c * 64 + (((ks2 * 4 + quad) ^ swzc) * 8);
            bf16x8 pfh = *(const bf16x8*)&Psh[wave][po];
            bf16x8 pfl = *(const bf16x8*)&Psl[wave][po];
#pragma unroll
            for (int dt = 0; dt < 8; ++dt) {
                int vrow = dt * 16 + c;
                int vo = vrow * 64 + (((ks2 * 4 + quad) ^ swz8(vrow)) * 8);
                bf16x8 vfh = *(const bf16x8*)&Vth[vo];
                bf16x8 vfl = *(const bf16x8*)&Vtl[vo];
                oacc[dt] = __builtin_amdgcn_mfma_f32_16x16x32_bf16(pfh, vfh, oacc[dt], 0, 0, 0);
                oacc[dt] = __builtin_amdgcn_mfma_f32_16x16x32_bf16(pfh, vfl, oacc[dt], 0, 0, 0);
                oacc[dt] = __builtin_amdgcn_mfma_f32_16x16x32_bf16(pfl, vfh, oacc[dt], 0, 0, 0);
            }
        }
        __syncthreads();
    }
#pragma unroll
    for (int dt = 0; dt < 8; ++dt)
#pragma unroll
        for (int r = 0; r < 4; ++r)
            ctx[(size_t)(q0w + quad * 4 + r) * H + hh * HD + dt * 16 + c] =
                oacc[dt][r] / li[r];
}

// ---------------- host ------------------------------------------------------
extern "C" void kernel_launch(void* const* d_in, const int* in_sizes, int n_in,
                              void* d_out, int out_size, void* d_ws, size_t ws_size,
                              hipStream_t stream) {
    const float* x_in = (const float*)d_in[0];
    const float* ln1 = (const float*)d_in[2];
    const float* ln2 = (const float*)d_in[3];
    const float* q_w = (const float*)d_in[4];  const float* q_b = (const float*)d_in[5];
    const float* k_w = (const float*)d_in[6];  const float* k_b = (const float*)d_in[7];
    const float* v_w = (const float*)d_in[8];  const float* v_b = (const float*)d_in[9];
    const float* o_w = (const float*)d_in[10]; const float* o_b = (const float*)d_in[11];
    const float* g_w = (const float*)d_in[12]; const float* g_b = (const float*)d_in[13];
    const float* u_w = (const float*)d_in[14]; const float* u_b = (const float*)d_in[15];
    const float* dn_w = (const float*)d_in[16]; const float* dn_b = (const float*)d_in[17];
    const int* pos = (const int*)d_in[18];
    float* out = (float*)d_out;

    const size_t SZ_WBUF = (size_t)INTER * H * 2;       // region sizes kept from
    const size_t SZ_H    = (size_t)S * H * 2;           //  the bf16 layout (roomy)
    const size_t SZ_SH4  = (size_t)S * H * 4;
    const size_t SZ_B    = (size_t)S * INTER * 4;
    const size_t OFF_H   = SZ_WBUF;
    const size_t OFF_B   = OFF_H + SZ_H;
    const size_t OFF_C   = OFF_B + SZ_B;
    const size_t OFF_TAB = OFF_C + 6 * SZ_H;
    if (ws_size < OFF_TAB + (size_t)S * 128 * 4) return;

    char* ws = (char*)d_ws;
    i8* wbuf    = (i8*)(ws);                       // i8 weights (<= 45MB)
    i8* h       = (i8*)(ws + OFF_H);               // i8 activations (8MB)
    // region B: q32+k32 -> ctx -> x2 (lifetimes disjoint)
    float* q32  = (float*)(ws + OFF_B);
    float* k32  = (float*)(ws + OFF_B + SZ_SH4);
    float* ctx  = (float*)(ws + OFF_B);
    float* x2   = (float*)(ws + OFF_B);
    // region C: q/k/v splits -> hid + act2
    u16* qh = (u16*)(ws + OFF_C);
    u16* ql = (u16*)(ws + OFF_C + SZ_H);
    u16* kh = (u16*)(ws + OFF_C + 2 * SZ_H);
    u16* kl = (u16*)(ws + OFF_C + 3 * SZ_H);
    u16* vh = (u16*)(ws + OFF_C + 4 * SZ_H);
    u16* vl = (u16*)(ws + OFF_C + 5 * SZ_H);
    float* hid = (float*)(ws + OFF_C);             // covers qh+ql (dead after attn)
    i8* act2   = (i8*)(ws + OFF_C + 3 * SZ_H);     // covers kl+vh (dead after attn)
    float* tab = (float*)(ws + OFF_TAB);

    dim3 b256(256);
    const int HH8 = H * H / 8;          // 2,097,152
    const int IH8 = INTER * H / 8;      // 5,636,096

    rope_table<<<dim3(S), dim3(64), 0, stream>>>(pos, tab);
    rmsnorm_csm_quant<<<dim3(S), b256, 0, stream>>>(x_in, ln1, h);

    // Q
    cvt_f32_i8<<<dim3(2048), b256, 0, stream>>>((const float4*)q_w, (uint2*)wbuf, HH8);
    gemm_i8<0><<<dim3(16, 32), b256, 0, stream>>>(h, wbuf, q_b, 2e-5f, H, H, q32, nullptr, nullptr, nullptr, nullptr);
    // K
    cvt_f32_i8<<<dim3(2048), b256, 0, stream>>>((const float4*)k_w, (uint2*)wbuf, HH8);
    gemm_i8<0><<<dim3(16, 32), b256, 0, stream>>>(h, wbuf, k_b, 2e-5f, H, H, k32, nullptr, nullptr, nullptr, nullptr);
    // V (store hi/lo split bf16)
    cvt_f32_i8<<<dim3(2048), b256, 0, stream>>>((const float4*)v_w, (uint2*)wbuf, HH8);
    gemm_i8<1><<<dim3(16, 32), b256, 0, stream>>>(h, wbuf, v_b, 2e-5f, H, H, nullptr, vh, vl, nullptr, nullptr);

    rope_apply<<<dim3(S * NH * 64 / 256), b256, 0, stream>>>(q32, k32, tab, qh, ql, kh, kl);
    attn<<<dim3(NH, S / 64), b256, 0, stream>>>(qh, ql, kh, kl, vh, vl, ctx);
    quant_to_i8<<<dim3(2048), b256, 0, stream>>>((const float4*)ctx, (unsigned*)h, S * H / 4);

    // O proj + residual (hid overlaps dead qh/ql)
    cvt_f32_i8<<<dim3(2048), b256, 0, stream>>>((const float4*)o_w, (uint2*)wbuf, HH8);
    gemm_i8<2><<<dim3(16, 32), b256, 0, stream>>>(h, wbuf, o_b, 2e-4f, H, H, hid, nullptr, nullptr, nullptr, x_in);

    rmsnorm_csm_quant<<<dim3(S), b256, 0, stream>>>(hid, ln2, h);

    // up
    cvt_f32_i8<<<dim3(2048), b256, 0, stream>>>((const float4*)u_w, (uint2*)wbuf, IH8);
    gemm_i8<0><<<dim3(16, 86), b256, 0, stream>>>(h, wbuf, u_b, 6e-5f, INTER, H, x2, nullptr, nullptr, nullptr, nullptr);
    // gate (+ silu * up + quant -> i8)
    cvt_f32_i8<<<dim3(2048), b256, 0, stream>>>((const float4*)g_w, (uint2*)wbuf, IH8);
    gemm_i8<3><<<dim3(16, 86), b256, 0, stream>>>(h, wbuf, g_b, 6e-5f, INTER, H, nullptr, nullptr, nullptr, act2, x2);
    // down + residual -> out
    cvt_f32_i8<<<dim3(2048), b256, 0, stream>>>((const float4*)dn_w, (uint2*)wbuf, IH8);
    gemm_i8<2><<<dim3(16, 32), b256, 0, stream>>>(act2, wbuf, dn_b, 2e-4f, H, INTER, out, nullptr, nullptr, nullptr, hid);
}